// Round 8
// baseline (2912.192 us; speedup 1.0000x reference)
//
#include <hip/hip_runtime.h>
#include <hip/hip_bf16.h>
#include <stdint.h>

#define HW 192
#define PLANE (HW * HW)
#define PH 194
#define PPG (PH * PH)      // 37636 granules per padded 8-ch plane
#define TS 16              // square spatial tile
#define HC 18              // halo cols/rows
#define HPX (HC * HC)      // 324 halo granules
#define HSTG 384           // staged granules (padded to 64-multiple)

typedef __attribute__((ext_vector_type(8))) short frag8;
typedef __attribute__((ext_vector_type(4))) float f32x4;
typedef unsigned short ushort_t;

__device__ __forceinline__ void split2(float v, ushort_t& h, ushort_t& l) {
    __hip_bfloat16 bh = __float2bfloat16(v);
    float hf = __bfloat162float(bh);
    __hip_bfloat16 bl = __float2bfloat16(v - hf);
    h = __builtin_bit_cast(ushort_t, bh);
    l = __builtin_bit_cast(ushort_t, bl);
}

// async 16B global->LDS copy: per-lane global src, wave-uniform LDS base (+lane*16)
__device__ __forceinline__ void gld_lds16(const ushort_t* g, ushort_t* s) {
    __builtin_amdgcn_global_load_lds(
        (const __attribute__((address_space(1))) uint32_t*)(const void*)g,
        (__attribute__((address_space(3))) uint32_t*)(void*)s, 16, 0, 0);
}

// W[O][C_IN][3][3] f32 -> wh/wl [NOB][NCHUNK][12][OTC][8] bf16 (taps 9..11, o>=C_OUT zero)
__global__ __launch_bounds__(256) void wtrans_kernel(
    const float* __restrict__ w, ushort_t* __restrict__ wh, ushort_t* __restrict__ wl,
    int C_IN, int C_OUT, int NCHUNK, int OTC, int total)
{
    for (int idx = blockIdx.x * 256 + threadIdx.x; idx < total; idx += gridDim.x * 256) {
        int ic = idx & 7;
        int g = idx >> 3;
        int o = g % OTC; g /= OTC;
        int t = g % 12;  g /= 12;
        int c8 = g % NCHUNK;
        int ob = g / NCHUNK;
        int og = ob * OTC + o;
        float v = 0.f;
        if (t < 9 && og < C_OUT)
            v = w[((size_t)og * C_IN + c8 * 8 + ic) * 9 + t];
        ushort_t h, l;
        split2(v, h, l);
        wh[idx] = h; wl[idx] = l;
    }
}

// fx [64][H][W] f32 -> padded hi/lo planes [8][PH][PH][8]
__global__ __launch_bounds__(256) void packfx_kernel(
    const float* __restrict__ src, ushort_t* __restrict__ dh, ushort_t* __restrict__ dl, int n)
{
    for (int idx = blockIdx.x * 256 + threadIdx.x; idx < n; idx += gridDim.x * 256) {
        int c = idx / PLANE;
        int p = idx - c * PLANE;
        int y = p / HW, x = p - y * HW;
        size_t di = ((size_t)(c >> 3) * PPG + (size_t)(y + 1) * PH + (x + 1)) * 8 + (c & 7);
        ushort_t h, l;
        split2(src[idx], h, l);
        dh[di] = h; dl[di] = l;
    }
}

// zero the 1-px borders of nchunks padded planes (both hi and lo tensors)
__global__ __launch_bounds__(256) void zborder_kernel(
    ushort_t* __restrict__ ph, ushort_t* __restrict__ pl, int nchunks)
{
    int total = nchunks * 772;
    for (int i = blockIdx.x * 256 + threadIdx.x; i < total; i += gridDim.x * 256) {
        int chunk = i / 772, b = i - chunk * 772;
        int y, x;
        if (b < 194)      { y = 0;   x = b; }
        else if (b < 388) { y = 193; x = b - 194; }
        else { int r = b - 388; y = 1 + (r >> 1); x = (r & 1) ? 193 : 0; }
        size_t g = ((size_t)chunk * PPG + (size_t)y * PH + x) * 8;
        uint4 z = make_uint4(0, 0, 0, 0);
        *(uint4*)&ph[g] = z;
        *(uint4*)&pl[g] = z;
    }
}

// 3x3 SAME conv via split-bf16 MFMA implicit GEMM. One batch image.
// inh/inl: [NCHUNK][PH][PH][8] bf16 padded planes; wh/wl: [NOB][NCHUNK][12][OTC][8].
// Block: 128 thr (2 waves), 16x16 spatial tile, OTC out channels (NF n-frags).
// K-chunk = 32 = 4 tap-slots x 8 ic; taps padded to 12 (slots 9..11 zero weights).
// Same contiguous-8 k-labeling for A and B fragments -> HW k-permutation cancels.
template<int NCHUNK, int OTC, bool LAST>
__global__ __launch_bounds__(128, 3) void conv_mfma(
    const ushort_t* __restrict__ inh, const ushort_t* __restrict__ inl,
    const ushort_t* __restrict__ wth, const ushort_t* __restrict__ wtl,
    const float* __restrict__ bias, int c_out,
    ushort_t* __restrict__ outh, ushort_t* __restrict__ outl, float* __restrict__ outf)
{
    constexpr int NF = OTC / 16;
    constexpr int NWIT = 12 * OTC / 64;   // weight staging iterations
    __shared__ ushort_t s_xh[HSTG * 8], s_xl[HSTG * 8];
    __shared__ ushort_t s_wh[12 * OTC * 8], s_wl[12 * OTC * 8];

    const int tid = threadIdx.x;
    const int wv = tid >> 6;          // 0..1
    const int lane = tid & 63;
    const int lq = lane >> 4;         // k-quarter / D-row group
    const int lr = lane & 15;         // A row (pixel) / B col (o) / D col
    const int tx0 = (blockIdx.x % 12) * TS;
    const int ty0 = (blockIdx.x / 12) * TS;
    const int ob = blockIdx.y;

    // per-lane halo granule for staging
    const int hp = lane;  // combined with j*64 below
    // per-lane tap offset (ushort units) into halo tile, per k-quad q
    int hof[3];
    #pragma unroll
    for (int q = 0; q < 3; ++q) {
        int t = q * 4 + lq;
        int te = t > 8 ? 8 : t;   // pad slots read tap8's (valid) address; B there is zero
        int dy = te >= 6 ? 2 : (te >= 3 ? 1 : 0);
        int dx = te - dy * 3;
        hof[q] = (dy * HC + dx) * 8;
    }

    f32x4 acc[8][NF];
    #pragma unroll
    for (int mf = 0; mf < 8; ++mf)
        #pragma unroll
        for (int nf = 0; nf < NF; ++nf) {
            int o = ob * OTC + nf * 16 + lr;
            float bv = (o < c_out) ? bias[o] : 0.f;
            acc[mf][nf] = (f32x4){bv, bv, bv, bv};
        }

    const ushort_t* wbh = wth + (size_t)ob * NCHUNK * 12 * OTC * 8;
    const ushort_t* wbl = wtl + (size_t)ob * NCHUNK * 12 * OTC * 8;

    for (int c8 = 0; c8 < NCHUNK; ++c8) {
        __syncthreads();
        // ---- stage input halo: 6 x 64-granule async copies (covers 324 + pad) ----
        const ushort_t* ih = inh + (size_t)c8 * PPG * 8;
        const ushort_t* il = inl + (size_t)c8 * PPG * 8;
        for (int j = wv; j < 6; j += 2) {
            int g0 = j * 64;
            int hg = g0 + hp;
            int r = hg / HC, c = hg - r * HC;
            size_t sg = ((size_t)(ty0 + r) * PH + (tx0 + c)) * 8;
            gld_lds16(&ih[sg], &s_xh[g0 * 8]);
            gld_lds16(&il[sg], &s_xl[g0 * 8]);
        }
        // ---- stage weights: contiguous [12][OTC][8] slab ----
        const ushort_t* wch = wbh + (size_t)c8 * 12 * OTC * 8;
        const ushort_t* wcl = wbl + (size_t)c8 * 12 * OTC * 8;
        for (int j = wv; j < NWIT; j += 2) {
            int g0 = j * 64;
            gld_lds16(&wch[(g0 + lane) * 8], &s_wh[g0 * 8]);
            gld_lds16(&wcl[(g0 + lane) * 8], &s_wl[g0 * 8]);
        }
        __syncthreads();   // drains vmcnt (compiler emits waitcnt before barrier)

        // ---- q-outer: B fragments in regs, sweep m-frags ----
        #pragma unroll
        for (int q = 0; q < 3; ++q) {
            int t = q * 4 + lq;
            frag8 bh[NF], bl[NF];
            #pragma unroll
            for (int nf = 0; nf < NF; ++nf) {
                int a = (t * OTC + nf * 16 + lr) * 8;
                bh[nf] = *(const frag8*)&s_wh[a];
                bl[nf] = *(const frag8*)&s_wl[a];
            }
            #pragma unroll
            for (int mf = 0; mf < 8; ++mf) {
                int abase = ((wv * 8 + mf) * HC + lr) * 8 + hof[q];
                frag8 ah = *(const frag8*)&s_xh[abase];
                frag8 al = *(const frag8*)&s_xl[abase];
                #pragma unroll
                for (int nf = 0; nf < NF; ++nf) {
                    acc[mf][nf] = __builtin_amdgcn_mfma_f32_16x16x32_bf16(ah, bh[nf], acc[mf][nf], 0, 0, 0);
                    acc[mf][nf] = __builtin_amdgcn_mfma_f32_16x16x32_bf16(ah, bl[nf], acc[mf][nf], 0, 0, 0);
                    acc[mf][nf] = __builtin_amdgcn_mfma_f32_16x16x32_bf16(al, bh[nf], acc[mf][nf], 0, 0, 0);
                }
            }
        }
    }

    // ---- epilogue: D row=(lq*4+j) -> x-offset, col=lr -> o ----
    #pragma unroll
    for (int mf = 0; mf < 8; ++mf) {
        int gy = ty0 + wv * 8 + mf;
        int px = tx0 + lq * 4;
        #pragma unroll
        for (int nf = 0; nf < NF; ++nf) {
            int o = ob * OTC + nf * 16 + lr;
            if (o < c_out) {
                if (LAST) {
                    float4 v = make_float4(acc[mf][nf][0], acc[mf][nf][1],
                                           acc[mf][nf][2], acc[mf][nf][3]);
                    *(float4*)&outf[(size_t)o * PLANE + gy * HW + px] = v;
                } else {
                    size_t g0 = ((size_t)(o >> 3) * PPG + (size_t)(gy + 1) * PH + (px + 1)) * 8 + (o & 7);
                    #pragma unroll
                    for (int j = 0; j < 4; ++j) {
                        ushort_t h, l;
                        split2(acc[mf][nf][j], h, l);
                        outh[g0 + (size_t)j * 8] = h;
                        outl[g0 + (size_t)j * 8] = l;
                    }
                }
            }
        }
    }
}

// One batch image. out[c,y,x] = sum_p ks[p*3+c, y, x] * xpad[c, y+p/5-2, x+p%5-2]
__global__ __launch_bounds__(256) void apply_kernel(
    const float* __restrict__ x, const float* __restrict__ ks,
    float* __restrict__ out)
{
    int tid = blockIdx.x * 256 + threadIdx.x;
    if (tid >= PLANE) return;
    int y = tid / HW;
    int xc = tid - y * HW;

    float acc[3] = {0.f, 0.f, 0.f};
    #pragma unroll
    for (int p = 0; p < 25; ++p) {
        const int di = p / 5, dj = p % 5;
        int yy = y + di - 2, xx = xc + dj - 2;
        bool inb = (yy >= 0 && yy < HW && xx >= 0 && xx < HW);
        #pragma unroll
        for (int c = 0; c < 3; ++c) {
            float kv = ks[((size_t)(p * 3 + c) * HW + y) * HW + xc];
            float xv = inb ? x[((size_t)c * HW + yy) * HW + xx] : 0.f;
            acc[c] = fmaf(kv, xv, acc[c]);
        }
    }
    #pragma unroll
    for (int c = 0; c < 3; ++c)
        out[((size_t)c * HW + y) * HW + xc] = acc[c];
}

extern "C" void kernel_launch(void* const* d_in, const int* in_sizes, int n_in,
                              void* d_out, int out_size, void* d_ws, size_t ws_size,
                              hipStream_t stream) {
    const float* feature_x = (const float*)d_in[0];
    const float* x  = (const float*)d_in[1];
    const float* W1 = (const float*)d_in[2];
    const float* b1 = (const float*)d_in[3];
    const float* W2 = (const float*)d_in[4];
    const float* b2 = (const float*)d_in[5];
    const float* W3 = (const float*)d_in[6];
    const float* b3 = (const float*)d_in[7];
    float* out = (float*)d_out;

    // workspace layout in ushort units, total ~93.7 MB
    const size_t PLN32 = (size_t)32 * PPG * 8;   // 9,634,816 ush
    const size_t PLN8  = (size_t)8 * PPG * 8;    // 2,408,704 ush
    ushort_t* y1h = (ushort_t*)d_ws;
    ushort_t* y1l = y1h + PLN32;
    ushort_t* y2h = y1l + PLN32;
    ushort_t* y2l = y2h + PLN32;
    ushort_t* shared_r = y2l + PLN32;            // max(fxh+fxl, ks) = 5,529,600 ush
    ushort_t* fxh = shared_r;
    ushort_t* fxl = fxh + PLN8;
    float*    ks  = (float*)shared_r;            // [75][PLANE] f32, aliases fx
    ushort_t* w1h = shared_r + 5529600;
    ushort_t* w1l = w1h + 221184;
    ushort_t* w2h = w1l + 221184;
    ushort_t* w2l = w2h + 884736;
    ushort_t* w3h = w2l + 884736;
    ushort_t* w3l = w3h + 294912;

    dim3 blk256(256), blk128(128);
    // zero padded borders of y1/y2 once (epilogues only write interiors)
    zborder_kernel<<<97, blk256, 0, stream>>>(y1h, y1l, 32);
    zborder_kernel<<<97, blk256, 0, stream>>>(y2h, y2l, 32);
    // weight transforms (shared across batches)
    wtrans_kernel<<<256, blk256, 0, stream>>>(W1, w1h, w1l, 64, 256, 8, 48, 221184);
    wtrans_kernel<<<256, blk256, 0, stream>>>(W2, w2h, w2l, 256, 256, 32, 48, 884736);
    wtrans_kernel<<<256, blk256, 0, stream>>>(W3, w3h, w3l, 256, 75, 32, 32, 294912);

    // 16x16 tiles: 12 x 12 = 144 spatial blocks
    dim3 g12(144, 6), g3(144, 3), ga((PLANE + 255) / 256);
    for (int b = 0; b < 4; ++b) {
        const float* fx_b = feature_x + (size_t)b * 64 * PLANE;
        const float* x_b  = x + (size_t)b * 3 * PLANE;
        float* out_b      = out + (size_t)b * 3 * PLANE;
        packfx_kernel<<<1024, blk256, 0, stream>>>(fx_b, fxh, fxl, 64 * PLANE);
        zborder_kernel<<<25, blk256, 0, stream>>>(fxh, fxl, 8);   // ks aliasing clobbers fx borders
        conv_mfma< 8, 48, false><<<g12, blk128, 0, stream>>>(fxh, fxl, w1h, w1l, b1, 256, y1h, y1l, nullptr);
        conv_mfma<32, 48, false><<<g12, blk128, 0, stream>>>(y1h, y1l, w2h, w2l, b2, 256, y2h, y2l, nullptr);
        conv_mfma<32, 32, true ><<<g3,  blk128, 0, stream>>>(y2h, y2l, w3h, w3l, b3,  75, nullptr, nullptr, ks);
        apply_kernel<<<ga, blk256, 0, stream>>>(x_b, ks, out_b);
    }
}

// Round 9
// 1527.624 us; speedup vs baseline: 1.9064x; 1.9064x over previous
//
#include <hip/hip_runtime.h>
#include <hip/hip_bf16.h>
#include <stdint.h>

#define HW 192
#define PLANE (HW * HW)
#define PH 194
#define PPG (PH * PH)      // 37636 granules per padded 8-ch plane
#define TS 16              // square spatial tile
#define HC 18              // halo cols/rows
#define HPX (HC * HC)      // 324 halo granules
#define HSTG 384           // staged granules (padded to 64-multiple)

typedef __attribute__((ext_vector_type(8))) short frag8;
typedef __attribute__((ext_vector_type(4))) float f32x4;
typedef unsigned short ushort_t;

__device__ __forceinline__ void split2(float v, ushort_t& h, ushort_t& l) {
    __hip_bfloat16 bh = __float2bfloat16(v);
    float hf = __bfloat162float(bh);
    __hip_bfloat16 bl = __float2bfloat16(v - hf);
    h = __builtin_bit_cast(ushort_t, bh);
    l = __builtin_bit_cast(ushort_t, bl);
}

// async 16B global->LDS copy: per-lane global src, wave-uniform LDS base (+lane*16)
__device__ __forceinline__ void gld_lds16(const ushort_t* g, ushort_t* s) {
    __builtin_amdgcn_global_load_lds(
        (const __attribute__((address_space(1))) uint32_t*)(const void*)g,
        (__attribute__((address_space(3))) uint32_t*)(void*)s, 16, 0, 0);
}

// W[O][C_IN][3][3] f32 -> wh/wl [NOB][NCHUNK][12][OTC][8] bf16 (taps 9..11, o>=C_OUT zero)
__global__ __launch_bounds__(256) void wtrans_kernel(
    const float* __restrict__ w, ushort_t* __restrict__ wh, ushort_t* __restrict__ wl,
    int C_IN, int C_OUT, int NCHUNK, int OTC, int total)
{
    for (int idx = blockIdx.x * 256 + threadIdx.x; idx < total; idx += gridDim.x * 256) {
        int ic = idx & 7;
        int g = idx >> 3;
        int o = g % OTC; g /= OTC;
        int t = g % 12;  g /= 12;
        int c8 = g % NCHUNK;
        int ob = g / NCHUNK;
        int og = ob * OTC + o;
        float v = 0.f;
        if (t < 9 && og < C_OUT)
            v = w[((size_t)og * C_IN + c8 * 8 + ic) * 9 + t];
        ushort_t h, l;
        split2(v, h, l);
        wh[idx] = h; wl[idx] = l;
    }
}

// fx [64][H][W] f32 -> padded hi/lo planes [8][PH][PH][8]
__global__ __launch_bounds__(256) void packfx_kernel(
    const float* __restrict__ src, ushort_t* __restrict__ dh, ushort_t* __restrict__ dl, int n)
{
    for (int idx = blockIdx.x * 256 + threadIdx.x; idx < n; idx += gridDim.x * 256) {
        int c = idx / PLANE;
        int p = idx - c * PLANE;
        int y = p / HW, x = p - y * HW;
        size_t di = ((size_t)(c >> 3) * PPG + (size_t)(y + 1) * PH + (x + 1)) * 8 + (c & 7);
        ushort_t h, l;
        split2(src[idx], h, l);
        dh[di] = h; dl[di] = l;
    }
}

// zero the 1-px borders of nchunks padded planes (both hi and lo tensors)
__global__ __launch_bounds__(256) void zborder_kernel(
    ushort_t* __restrict__ ph, ushort_t* __restrict__ pl, int nchunks)
{
    int total = nchunks * 772;
    for (int i = blockIdx.x * 256 + threadIdx.x; i < total; i += gridDim.x * 256) {
        int chunk = i / 772, b = i - chunk * 772;
        int y, x;
        if (b < 194)      { y = 0;   x = b; }
        else if (b < 388) { y = 193; x = b - 194; }
        else { int r = b - 388; y = 1 + (r >> 1); x = (r & 1) ? 193 : 0; }
        size_t g = ((size_t)chunk * PPG + (size_t)y * PH + x) * 8;
        uint4 z = make_uint4(0, 0, 0, 0);
        *(uint4*)&ph[g] = z;
        *(uint4*)&pl[g] = z;
    }
}

// 3x3 SAME conv via split-bf16 MFMA implicit GEMM. One batch image.
// inh/inl: [NCHUNK][PH][PH][8] bf16 padded planes; wh/wl: [NOB][NCHUNK][12][OTC][8].
// Block: 128 thr (2 waves), 16x16 spatial tile, OTC out channels (NF n-frags).
// K-chunk = 32 = 4 tap-slots x 8 ic; taps padded to 12 (slots 9..11 zero weights).
// Same contiguous-8 k-labeling for A and B fragments -> HW k-permutation cancels.
// NOTE: no min-waves hint — (128,3) drove VGPR to 84 (< acc footprint 96) -> spill (round 8).
template<int NCHUNK, int OTC, bool LAST>
__global__ __launch_bounds__(128) void conv_mfma(
    const ushort_t* __restrict__ inh, const ushort_t* __restrict__ inl,
    const ushort_t* __restrict__ wth, const ushort_t* __restrict__ wtl,
    const float* __restrict__ bias, int c_out,
    ushort_t* __restrict__ outh, ushort_t* __restrict__ outl, float* __restrict__ outf)
{
    constexpr int NF = OTC / 16;
    constexpr int NWIT = 12 * OTC / 64;   // weight staging iterations
    __shared__ ushort_t s_xh[HSTG * 8], s_xl[HSTG * 8];
    __shared__ ushort_t s_wh[12 * OTC * 8], s_wl[12 * OTC * 8];

    const int tid = threadIdx.x;
    const int wv = tid >> 6;          // 0..1
    const int lane = tid & 63;
    const int lq = lane >> 4;         // k-quarter / D-row group
    const int lr = lane & 15;         // A row (pixel) / B col (o) / D col
    const int tx0 = (blockIdx.x % 12) * TS;
    const int ty0 = (blockIdx.x / 12) * TS;
    const int ob = blockIdx.y;

    const int hp = lane;
    // per-lane tap offset (ushort units) into halo tile, per k-quad q
    int hof[3];
    #pragma unroll
    for (int q = 0; q < 3; ++q) {
        int t = q * 4 + lq;
        int te = t > 8 ? 8 : t;   // pad slots read tap8's (valid) address; B there is zero
        int dy = te >= 6 ? 2 : (te >= 3 ? 1 : 0);
        int dx = te - dy * 3;
        hof[q] = (dy * HC + dx) * 8;
    }

    f32x4 acc[8][NF];
    #pragma unroll
    for (int mf = 0; mf < 8; ++mf)
        #pragma unroll
        for (int nf = 0; nf < NF; ++nf) {
            int o = ob * OTC + nf * 16 + lr;
            float bv = (o < c_out) ? bias[o] : 0.f;
            acc[mf][nf] = (f32x4){bv, bv, bv, bv};
        }

    const ushort_t* wbh = wth + (size_t)ob * NCHUNK * 12 * OTC * 8;
    const ushort_t* wbl = wtl + (size_t)ob * NCHUNK * 12 * OTC * 8;

    for (int c8 = 0; c8 < NCHUNK; ++c8) {
        __syncthreads();
        // ---- stage input halo: 6 x 64-granule async copies (covers 324 + pad) ----
        const ushort_t* ih = inh + (size_t)c8 * PPG * 8;
        const ushort_t* il = inl + (size_t)c8 * PPG * 8;
        for (int j = wv; j < 6; j += 2) {
            int g0 = j * 64;
            int hg = g0 + hp;
            int r = hg / HC, c = hg - r * HC;
            size_t sg = ((size_t)(ty0 + r) * PH + (tx0 + c)) * 8;
            gld_lds16(&ih[sg], &s_xh[g0 * 8]);
            gld_lds16(&il[sg], &s_xl[g0 * 8]);
        }
        // ---- stage weights: contiguous [12][OTC][8] slab ----
        const ushort_t* wch = wbh + (size_t)c8 * 12 * OTC * 8;
        const ushort_t* wcl = wbl + (size_t)c8 * 12 * OTC * 8;
        for (int j = wv; j < NWIT; j += 2) {
            int g0 = j * 64;
            gld_lds16(&wch[(g0 + lane) * 8], &s_wh[g0 * 8]);
            gld_lds16(&wcl[(g0 + lane) * 8], &s_wl[g0 * 8]);
        }
        __syncthreads();   // drains vmcnt (compiler emits waitcnt before barrier)

        // ---- q-outer: B fragments in regs, sweep m-frags ----
        #pragma unroll
        for (int q = 0; q < 3; ++q) {
            int t = q * 4 + lq;
            frag8 bh[NF], bl[NF];
            #pragma unroll
            for (int nf = 0; nf < NF; ++nf) {
                int a = (t * OTC + nf * 16 + lr) * 8;
                bh[nf] = *(const frag8*)&s_wh[a];
                bl[nf] = *(const frag8*)&s_wl[a];
            }
            #pragma unroll
            for (int mf = 0; mf < 8; ++mf) {
                int abase = ((wv * 8 + mf) * HC + lr) * 8 + hof[q];
                frag8 ah = *(const frag8*)&s_xh[abase];
                frag8 al = *(const frag8*)&s_xl[abase];
                #pragma unroll
                for (int nf = 0; nf < NF; ++nf) {
                    acc[mf][nf] = __builtin_amdgcn_mfma_f32_16x16x32_bf16(ah, bh[nf], acc[mf][nf], 0, 0, 0);
                    acc[mf][nf] = __builtin_amdgcn_mfma_f32_16x16x32_bf16(ah, bl[nf], acc[mf][nf], 0, 0, 0);
                    acc[mf][nf] = __builtin_amdgcn_mfma_f32_16x16x32_bf16(al, bh[nf], acc[mf][nf], 0, 0, 0);
                }
            }
        }
    }

    // ---- epilogue: D row=(lq*4+j) -> x-offset, col=lr -> o ----
    #pragma unroll
    for (int mf = 0; mf < 8; ++mf) {
        int gy = ty0 + wv * 8 + mf;
        int px = tx0 + lq * 4;
        #pragma unroll
        for (int nf = 0; nf < NF; ++nf) {
            int o = ob * OTC + nf * 16 + lr;
            if (o < c_out) {
                if (LAST) {
                    float4 v = make_float4(acc[mf][nf][0], acc[mf][nf][1],
                                           acc[mf][nf][2], acc[mf][nf][3]);
                    *(float4*)&outf[(size_t)o * PLANE + gy * HW + px] = v;
                } else {
                    size_t g0 = ((size_t)(o >> 3) * PPG + (size_t)(gy + 1) * PH + (px + 1)) * 8 + (o & 7);
                    #pragma unroll
                    for (int j = 0; j < 4; ++j) {
                        ushort_t h, l;
                        split2(acc[mf][nf][j], h, l);
                        outh[g0 + (size_t)j * 8] = h;
                        outl[g0 + (size_t)j * 8] = l;
                    }
                }
            }
        }
    }
}

// One batch image. out[c,y,x] = sum_p ks[p*3+c, y, x] * xpad[c, y+p/5-2, x+p%5-2]
__global__ __launch_bounds__(256) void apply_kernel(
    const float* __restrict__ x, const float* __restrict__ ks,
    float* __restrict__ out)
{
    int tid = blockIdx.x * 256 + threadIdx.x;
    if (tid >= PLANE) return;
    int y = tid / HW;
    int xc = tid - y * HW;

    float acc[3] = {0.f, 0.f, 0.f};
    #pragma unroll
    for (int p = 0; p < 25; ++p) {
        const int di = p / 5, dj = p % 5;
        int yy = y + di - 2, xx = xc + dj - 2;
        bool inb = (yy >= 0 && yy < HW && xx >= 0 && xx < HW);
        #pragma unroll
        for (int c = 0; c < 3; ++c) {
            float kv = ks[((size_t)(p * 3 + c) * HW + y) * HW + xc];
            float xv = inb ? x[((size_t)c * HW + yy) * HW + xx] : 0.f;
            acc[c] = fmaf(kv, xv, acc[c]);
        }
    }
    #pragma unroll
    for (int c = 0; c < 3; ++c)
        out[((size_t)c * HW + y) * HW + xc] = acc[c];
}

extern "C" void kernel_launch(void* const* d_in, const int* in_sizes, int n_in,
                              void* d_out, int out_size, void* d_ws, size_t ws_size,
                              hipStream_t stream) {
    const float* feature_x = (const float*)d_in[0];
    const float* x  = (const float*)d_in[1];
    const float* W1 = (const float*)d_in[2];
    const float* b1 = (const float*)d_in[3];
    const float* W2 = (const float*)d_in[4];
    const float* b2 = (const float*)d_in[5];
    const float* W3 = (const float*)d_in[6];
    const float* b3 = (const float*)d_in[7];
    float* out = (float*)d_out;

    // workspace layout in ushort units, total ~93.7 MB
    const size_t PLN32 = (size_t)32 * PPG * 8;   // 9,634,816 ush
    const size_t PLN8  = (size_t)8 * PPG * 8;    // 2,408,704 ush
    ushort_t* y1h = (ushort_t*)d_ws;
    ushort_t* y1l = y1h + PLN32;
    ushort_t* y2h = y1l + PLN32;
    ushort_t* y2l = y2h + PLN32;
    ushort_t* shared_r = y2l + PLN32;            // max(fxh+fxl, ks) = 5,529,600 ush
    ushort_t* fxh = shared_r;
    ushort_t* fxl = fxh + PLN8;
    float*    ks  = (float*)shared_r;            // [75][PLANE] f32, aliases fx
    ushort_t* w1h = shared_r + 5529600;
    ushort_t* w1l = w1h + 221184;
    ushort_t* w2h = w1l + 221184;
    ushort_t* w2l = w2h + 884736;
    ushort_t* w3h = w2l + 884736;
    ushort_t* w3l = w3h + 294912;

    dim3 blk256(256), blk128(128);
    // zero padded borders of y1/y2 once (epilogues only write interiors)
    zborder_kernel<<<97, blk256, 0, stream>>>(y1h, y1l, 32);
    zborder_kernel<<<97, blk256, 0, stream>>>(y2h, y2l, 32);
    // weight transforms (shared across batches)
    wtrans_kernel<<<256, blk256, 0, stream>>>(W1, w1h, w1l, 64, 256, 8, 48, 221184);
    wtrans_kernel<<<256, blk256, 0, stream>>>(W2, w2h, w2l, 256, 256, 32, 48, 884736);
    wtrans_kernel<<<256, blk256, 0, stream>>>(W3, w3h, w3l, 256, 75, 32, 32, 294912);

    // 16x16 tiles: 12 x 12 = 144 spatial blocks
    dim3 g12(144, 6), g3(144, 3), ga((PLANE + 255) / 256);
    for (int b = 0; b < 4; ++b) {
        const float* fx_b = feature_x + (size_t)b * 64 * PLANE;
        const float* x_b  = x + (size_t)b * 3 * PLANE;
        float* out_b      = out + (size_t)b * 3 * PLANE;
        packfx_kernel<<<1024, blk256, 0, stream>>>(fx_b, fxh, fxl, 64 * PLANE);
        zborder_kernel<<<25, blk256, 0, stream>>>(fxh, fxl, 8);   // ks aliasing clobbers fx borders
        conv_mfma< 8, 48, false><<<g12, blk128, 0, stream>>>(fxh, fxl, w1h, w1l, b1, 256, y1h, y1l, nullptr);
        conv_mfma<32, 48, false><<<g12, blk128, 0, stream>>>(y1h, y1l, w2h, w2l, b2, 256, y2h, y2l, nullptr);
        conv_mfma<32, 32, true ><<<g3,  blk128, 0, stream>>>(y2h, y2l, w3h, w3l, b3,  75, nullptr, nullptr, ks);
        apply_kernel<<<ga, blk256, 0, stream>>>(x_b, ks, out_b);
    }
}

// Round 10
// 1257.640 us; speedup vs baseline: 2.3156x; 1.2147x over previous
//
#include <hip/hip_runtime.h>
#include <hip/hip_bf16.h>
#include <stdint.h>

#define HW 192
#define PLANE (HW * HW)
#define PH 194
#define PPG (PH * PH)      // 37636 granules per padded 8-ch plane
#define TSX 32             // tile cols
#define TSY 16             // tile rows
#define HCC 34             // halo cols
#define HRR 18             // halo rows
#define HGR (HRR * HCC)    // 612 halo granules

typedef __attribute__((ext_vector_type(8))) short frag8;
typedef __attribute__((ext_vector_type(4))) float f32x4;
typedef unsigned short ushort_t;

__device__ __forceinline__ void split2(float v, ushort_t& h, ushort_t& l) {
    __hip_bfloat16 bh = __float2bfloat16(v);
    float hf = __bfloat162float(bh);
    __hip_bfloat16 bl = __float2bfloat16(v - hf);
    h = __builtin_bit_cast(ushort_t, bh);
    l = __builtin_bit_cast(ushort_t, bl);
}

// async 16B global->LDS copy: per-lane global src, wave-uniform LDS base (+lane*16)
__device__ __forceinline__ void gld_lds16(const ushort_t* g, ushort_t* s) {
    __builtin_amdgcn_global_load_lds(
        (const __attribute__((address_space(1))) uint32_t*)(const void*)g,
        (__attribute__((address_space(3))) uint32_t*)(void*)s, 16, 0, 0);
}

// W[O][C_IN][3][3] f32 -> wh/wl [NOB][NCHUNK][12][OTC][8] bf16 (taps 9..11, o>=C_OUT zero)
__global__ __launch_bounds__(256) void wtrans_kernel(
    const float* __restrict__ w, ushort_t* __restrict__ wh, ushort_t* __restrict__ wl,
    int C_IN, int C_OUT, int NCHUNK, int OTC, int total)
{
    for (int idx = blockIdx.x * 256 + threadIdx.x; idx < total; idx += gridDim.x * 256) {
        int ic = idx & 7;
        int g = idx >> 3;
        int o = g % OTC; g /= OTC;
        int t = g % 12;  g /= 12;
        int c8 = g % NCHUNK;
        int ob = g / NCHUNK;
        int og = ob * OTC + o;
        float v = 0.f;
        if (t < 9 && og < C_OUT)
            v = w[((size_t)og * C_IN + c8 * 8 + ic) * 9 + t];
        ushort_t h, l;
        split2(v, h, l);
        wh[idx] = h; wl[idx] = l;
    }
}

// fx [64][H][W] f32 -> padded hi/lo planes [8][PH][PH][8]
__global__ __launch_bounds__(256) void packfx_kernel(
    const float* __restrict__ src, ushort_t* __restrict__ dh, ushort_t* __restrict__ dl, int n)
{
    for (int idx = blockIdx.x * 256 + threadIdx.x; idx < n; idx += gridDim.x * 256) {
        int c = idx / PLANE;
        int p = idx - c * PLANE;
        int y = p / HW, x = p - y * HW;
        size_t di = ((size_t)(c >> 3) * PPG + (size_t)(y + 1) * PH + (x + 1)) * 8 + (c & 7);
        ushort_t h, l;
        split2(src[idx], h, l);
        dh[di] = h; dl[di] = l;
    }
}

// zero the 1-px borders of nchunks padded planes (both hi and lo tensors)
__global__ __launch_bounds__(256) void zborder_kernel(
    ushort_t* __restrict__ ph, ushort_t* __restrict__ pl, int nchunks)
{
    int total = nchunks * 772;
    for (int i = blockIdx.x * 256 + threadIdx.x; i < total; i += gridDim.x * 256) {
        int chunk = i / 772, b = i - chunk * 772;
        int y, x;
        if (b < 194)      { y = 0;   x = b; }
        else if (b < 388) { y = 193; x = b - 194; }
        else { int r = b - 388; y = 1 + (r >> 1); x = (r & 1) ? 193 : 0; }
        size_t g = ((size_t)chunk * PPG + (size_t)y * PH + x) * 8;
        uint4 z = make_uint4(0, 0, 0, 0);
        *(uint4*)&ph[g] = z;
        *(uint4*)&pl[g] = z;
    }
}

// 3x3 SAME conv via split-bf16 MFMA implicit GEMM, double-buffered LDS prefetch.
// inh/inl: [NCHUNK][PH][PH][8] bf16 padded planes; wh/wl: [NOB][NCHUNK][12][OTC][8].
// Block: 256 thr (4 waves), 16(rows)x32(cols) spatial tile, OTC out channels.
// K-chunk = 32 = 4 tap-slots x 8 ic; taps padded to 12 (slots 9..11 zero weights).
// T3-minimum pipeline: STAGE(next buf) issued before compute(cur); one barrier
// per chunk (its implicit vmcnt(0) drain lands after ~2000cy of MFMA).
// NOTE: no min-waves hint (rounds 5/8: hint under acc footprint -> spill).
template<int NCHUNK, int OTC, bool LAST>
__global__ __launch_bounds__(256) void conv_mfma(
    const ushort_t* __restrict__ inh, const ushort_t* __restrict__ inl,
    const ushort_t* __restrict__ wth, const ushort_t* __restrict__ wtl,
    const float* __restrict__ bias, int c_out,
    ushort_t* __restrict__ outh, ushort_t* __restrict__ outl, float* __restrict__ outf)
{
    constexpr int NF = OTC / 16;
    constexpr int WSLAB = 12 * OTC * 8;       // ush per weight buffer
    constexpr int NWIT = WSLAB / 512;         // 64-granule staging iters (exact)
    __shared__ ushort_t s_xh[2 * HGR * 8], s_xl[2 * HGR * 8];   // 2 x 9792 B each
    __shared__ ushort_t s_wh[2 * WSLAB],   s_wl[2 * WSLAB];     // 2 x 6144 B each (OTC=32)

    const int tid = threadIdx.x;
    const int wv = tid >> 6;          // 0..3
    const int lane = tid & 63;
    const int lq = lane >> 4;         // k-quarter / D-row group
    const int lr = lane & 15;         // A row (pixel) / B col (o) / D col
    const int tx0 = (blockIdx.x % 6) * TSX;
    const int ty0 = (blockIdx.x / 6) * TSY;
    const int ob = blockIdx.y;
    // wave -> sub-tile: rows (wv>>1)*8..+8, col-half (wv&1)*16
    const int wrow = (wv >> 1) * 8;
    const int wcol = (wv & 1) * 16;

    // per-lane tap offset (ushort units) into halo tile, per k-quad q
    int hof[3];
    #pragma unroll
    for (int q = 0; q < 3; ++q) {
        int t = q * 4 + lq;
        int te = t > 8 ? 8 : t;   // pad slots read tap8's (valid) address; B there is zero
        int dy = te >= 6 ? 2 : (te >= 3 ? 1 : 0);
        int dx = te - dy * 3;
        hof[q] = (dy * HCC + dx) * 8;
    }

    f32x4 acc[8][NF];
    #pragma unroll
    for (int mf = 0; mf < 8; ++mf)
        #pragma unroll
        for (int nf = 0; nf < NF; ++nf) {
            int o = ob * OTC + nf * 16 + lr;
            float bv = (o < c_out) ? bias[o] : 0.f;
            acc[mf][nf] = (f32x4){bv, bv, bv, bv};
        }

    const ushort_t* wbh = wth + (size_t)ob * NCHUNK * 12 * OTC * 8;
    const ushort_t* wbl = wtl + (size_t)ob * NCHUNK * 12 * OTC * 8;

    auto stage = [&](int buf, int c8) {
        const ushort_t* ih = inh + (size_t)c8 * PPG * 8;
        const ushort_t* il = inl + (size_t)c8 * PPG * 8;
        ushort_t* dxh = s_xh + buf * (HGR * 8);
        ushort_t* dxl = s_xl + buf * (HGR * 8);
        // halo: 612 granules in 10 x 64-lane iters (last iter 36 lanes active)
        for (int j = wv; j < 10; j += 4) {
            int hg = j * 64 + lane;
            if (hg < HGR) {
                int r = hg / HCC, c = hg - r * HCC;
                size_t sg = ((size_t)(ty0 + r) * PH + (tx0 + c)) * 8;
                gld_lds16(&ih[sg], &dxh[j * 64 * 8]);
                gld_lds16(&il[sg], &dxl[j * 64 * 8]);
            }
        }
        const ushort_t* wch = wbh + (size_t)c8 * WSLAB;
        const ushort_t* wcl = wbl + (size_t)c8 * WSLAB;
        ushort_t* dwh = s_wh + buf * WSLAB;
        ushort_t* dwl = s_wl + buf * WSLAB;
        for (int j = wv; j < NWIT; j += 4) {
            gld_lds16(&wch[(j * 64 + lane) * 8], &dwh[j * 64 * 8]);
            gld_lds16(&wcl[(j * 64 + lane) * 8], &dwl[j * 64 * 8]);
        }
    };

    stage(0, 0);
    __syncthreads();   // drains vmcnt -> buf0 ready

    int cur = 0;
    for (int c8 = 0; c8 < NCHUNK; ++c8) {
        if (c8 + 1 < NCHUNK) stage(cur ^ 1, c8 + 1);   // async prefetch, other buffer

        const ushort_t* xh = s_xh + cur * (HGR * 8);
        const ushort_t* xl = s_xl + cur * (HGR * 8);
        const ushort_t* wh = s_wh + cur * WSLAB;
        const ushort_t* wl = s_wl + cur * WSLAB;
        #pragma unroll
        for (int q = 0; q < 3; ++q) {
            int t = q * 4 + lq;
            frag8 bh[NF], bl[NF];
            #pragma unroll
            for (int nf = 0; nf < NF; ++nf) {
                int a = (t * OTC + nf * 16 + lr) * 8;
                bh[nf] = *(const frag8*)&wh[a];
                bl[nf] = *(const frag8*)&wl[a];
            }
            #pragma unroll
            for (int mf = 0; mf < 8; ++mf) {
                int abase = ((wrow + mf) * HCC + wcol + lr) * 8 + hof[q];
                frag8 ah = *(const frag8*)&xh[abase];
                frag8 al = *(const frag8*)&xl[abase];
                #pragma unroll
                for (int nf = 0; nf < NF; ++nf) {
                    acc[mf][nf] = __builtin_amdgcn_mfma_f32_16x16x32_bf16(ah, bh[nf], acc[mf][nf], 0, 0, 0);
                    acc[mf][nf] = __builtin_amdgcn_mfma_f32_16x16x32_bf16(ah, bl[nf], acc[mf][nf], 0, 0, 0);
                    acc[mf][nf] = __builtin_amdgcn_mfma_f32_16x16x32_bf16(al, bh[nf], acc[mf][nf], 0, 0, 0);
                }
            }
        }
        __syncthreads();   // joins waves on cur + drains prefetch vmcnt -> next buf ready
        cur ^= 1;
    }

    // ---- epilogue: D row=(lq*4+j) -> x-offset, col=lr -> o ----
    #pragma unroll
    for (int mf = 0; mf < 8; ++mf) {
        int gy = ty0 + wrow + mf;
        int px = tx0 + wcol + lq * 4;
        #pragma unroll
        for (int nf = 0; nf < NF; ++nf) {
            int o = ob * OTC + nf * 16 + lr;
            if (o < c_out) {
                if (LAST) {
                    float4 v = make_float4(acc[mf][nf][0], acc[mf][nf][1],
                                           acc[mf][nf][2], acc[mf][nf][3]);
                    *(float4*)&outf[(size_t)o * PLANE + gy * HW + px] = v;
                } else {
                    size_t g0 = ((size_t)(o >> 3) * PPG + (size_t)(gy + 1) * PH + (px + 1)) * 8 + (o & 7);
                    #pragma unroll
                    for (int j = 0; j < 4; ++j) {
                        ushort_t h, l;
                        split2(acc[mf][nf][j], h, l);
                        outh[g0 + (size_t)j * 8] = h;
                        outl[g0 + (size_t)j * 8] = l;
                    }
                }
            }
        }
    }
}

// One batch image. out[c,y,x] = sum_p ks[p*3+c, y, x] * xpad[c, y+p/5-2, x+p%5-2]
__global__ __launch_bounds__(256) void apply_kernel(
    const float* __restrict__ x, const float* __restrict__ ks,
    float* __restrict__ out)
{
    int tid = blockIdx.x * 256 + threadIdx.x;
    if (tid >= PLANE) return;
    int y = tid / HW;
    int xc = tid - y * HW;

    float acc[3] = {0.f, 0.f, 0.f};
    #pragma unroll
    for (int p = 0; p < 25; ++p) {
        const int di = p / 5, dj = p % 5;
        int yy = y + di - 2, xx = xc + dj - 2;
        bool inb = (yy >= 0 && yy < HW && xx >= 0 && xx < HW);
        #pragma unroll
        for (int c = 0; c < 3; ++c) {
            float kv = ks[((size_t)(p * 3 + c) * HW + y) * HW + xc];
            float xv = inb ? x[((size_t)c * HW + yy) * HW + xx] : 0.f;
            acc[c] = fmaf(kv, xv, acc[c]);
        }
    }
    #pragma unroll
    for (int c = 0; c < 3; ++c)
        out[((size_t)c * HW + y) * HW + xc] = acc[c];
}

extern "C" void kernel_launch(void* const* d_in, const int* in_sizes, int n_in,
                              void* d_out, int out_size, void* d_ws, size_t ws_size,
                              hipStream_t stream) {
    const float* feature_x = (const float*)d_in[0];
    const float* x  = (const float*)d_in[1];
    const float* W1 = (const float*)d_in[2];
    const float* b1 = (const float*)d_in[3];
    const float* W2 = (const float*)d_in[4];
    const float* b2 = (const float*)d_in[5];
    const float* W3 = (const float*)d_in[6];
    const float* b3 = (const float*)d_in[7];
    float* out = (float*)d_out;

    // workspace layout in ushort units, total ~93.2 MB
    const size_t PLN32 = (size_t)32 * PPG * 8;   // 9,634,816 ush
    const size_t PLN8  = (size_t)8 * PPG * 8;    // 2,408,704 ush
    ushort_t* y1h = (ushort_t*)d_ws;
    ushort_t* y1l = y1h + PLN32;
    ushort_t* y2h = y1l + PLN32;
    ushort_t* y2l = y2h + PLN32;
    ushort_t* shared_r = y2l + PLN32;            // max(fxh+fxl, ks) = 5,529,600 ush
    ushort_t* fxh = shared_r;
    ushort_t* fxl = fxh + PLN8;
    float*    ks  = (float*)shared_r;            // [75][PLANE] f32, aliases fx
    ushort_t* w1h = shared_r + 5529600;          // [8][8][12][32][8]  = 196,608
    ushort_t* w1l = w1h + 196608;
    ushort_t* w2h = w1l + 196608;                // [8][32][12][32][8] = 786,432
    ushort_t* w2l = w2h + 786432;
    ushort_t* w3h = w2l + 786432;                // [3][32][12][32][8] = 294,912
    ushort_t* w3l = w3h + 294912;

    dim3 blk256(256);
    // zero padded borders of y1/y2 once (epilogues only write interiors)
    zborder_kernel<<<97, blk256, 0, stream>>>(y1h, y1l, 32);
    zborder_kernel<<<97, blk256, 0, stream>>>(y2h, y2l, 32);
    // weight transforms (shared across batches)
    wtrans_kernel<<<256, blk256, 0, stream>>>(W1, w1h, w1l, 64, 256, 8, 32, 196608);
    wtrans_kernel<<<256, blk256, 0, stream>>>(W2, w2h, w2l, 256, 256, 32, 32, 786432);
    wtrans_kernel<<<256, blk256, 0, stream>>>(W3, w3h, w3l, 256, 75, 32, 32, 294912);

    // 16x32 tiles: 6 x-tiles, 12 y-tiles = 72 spatial blocks
    dim3 g12(72, 8), g3(72, 3), ga((PLANE + 255) / 256);
    for (int b = 0; b < 4; ++b) {
        const float* fx_b = feature_x + (size_t)b * 64 * PLANE;
        const float* x_b  = x + (size_t)b * 3 * PLANE;
        float* out_b      = out + (size_t)b * 3 * PLANE;
        packfx_kernel<<<1024, blk256, 0, stream>>>(fx_b, fxh, fxl, 64 * PLANE);
        zborder_kernel<<<25, blk256, 0, stream>>>(fxh, fxl, 8);   // ks aliasing clobbers fx borders
        conv_mfma< 8, 32, false><<<g12, blk256, 0, stream>>>(fxh, fxl, w1h, w1l, b1, 256, y1h, y1l, nullptr);
        conv_mfma<32, 32, false><<<g12, blk256, 0, stream>>>(y1h, y1l, w2h, w2l, b2, 256, y2h, y2l, nullptr);
        conv_mfma<32, 32, true ><<<g3,  blk256, 0, stream>>>(y2h, y2l, w3h, w3l, b3,  75, nullptr, nullptr, ks);
        apply_kernel<<<ga, blk256, 0, stream>>>(x_b, ks, out_b);
    }
}

// Round 11
// 1125.661 us; speedup vs baseline: 2.5871x; 1.1172x over previous
//
#include <hip/hip_runtime.h>
#include <hip/hip_bf16.h>
#include <stdint.h>

#define HW 192
#define PLANE (HW * HW)
#define PH 194
#define PPG (PH * PH)      // 37636 granules per padded 8-ch plane
#define TS 16              // square spatial tile
#define HC 18              // halo cols/rows
#define HGR (HC * HC)      // 324 halo granules

typedef __attribute__((ext_vector_type(8))) short frag8;
typedef __attribute__((ext_vector_type(16))) float f32x16;
typedef unsigned short ushort_t;

__device__ __forceinline__ void split2(float v, ushort_t& h, ushort_t& l) {
    __hip_bfloat16 bh = __float2bfloat16(v);
    float hf = __bfloat162float(bh);
    __hip_bfloat16 bl = __float2bfloat16(v - hf);
    h = __builtin_bit_cast(ushort_t, bh);
    l = __builtin_bit_cast(ushort_t, bl);
}

// async 16B global->LDS copy: per-lane global src, wave-uniform LDS base (+lane*16)
__device__ __forceinline__ void gld_lds16(const ushort_t* g, ushort_t* s) {
    __builtin_amdgcn_global_load_lds(
        (const __attribute__((address_space(1))) uint32_t*)(const void*)g,
        (__attribute__((address_space(3))) uint32_t*)(void*)s, 16, 0, 0);
}

// W[O][C_IN][3][3] f32 -> wh/wl [NOB][NCHUNK][10][OTC][8] bf16 (tap slot 9 and o>=C_OUT zero)
__global__ __launch_bounds__(256) void wtrans_kernel(
    const float* __restrict__ w, ushort_t* __restrict__ wh, ushort_t* __restrict__ wl,
    int C_IN, int C_OUT, int NCHUNK, int OTC, int total)
{
    for (int idx = blockIdx.x * 256 + threadIdx.x; idx < total; idx += gridDim.x * 256) {
        int ic = idx & 7;
        int g = idx >> 3;
        int o = g % OTC; g /= OTC;
        int t = g % 10;  g /= 10;
        int c8 = g % NCHUNK;
        int ob = g / NCHUNK;
        int og = ob * OTC + o;
        float v = 0.f;
        if (t < 9 && og < C_OUT)
            v = w[((size_t)og * C_IN + c8 * 8 + ic) * 9 + t];
        ushort_t h, l;
        split2(v, h, l);
        wh[idx] = h; wl[idx] = l;
    }
}

// fx [64][H][W] f32 -> padded hi/lo planes [8][PH][PH][8]
__global__ __launch_bounds__(256) void packfx_kernel(
    const float* __restrict__ src, ushort_t* __restrict__ dh, ushort_t* __restrict__ dl, int n)
{
    for (int idx = blockIdx.x * 256 + threadIdx.x; idx < n; idx += gridDim.x * 256) {
        int c = idx / PLANE;
        int p = idx - c * PLANE;
        int y = p / HW, x = p - y * HW;
        size_t di = ((size_t)(c >> 3) * PPG + (size_t)(y + 1) * PH + (x + 1)) * 8 + (c & 7);
        ushort_t h, l;
        split2(src[idx], h, l);
        dh[di] = h; dl[di] = l;
    }
}

// zero the 1-px borders of nchunks padded planes (both hi and lo tensors)
__global__ __launch_bounds__(256) void zborder_kernel(
    ushort_t* __restrict__ ph, ushort_t* __restrict__ pl, int nchunks)
{
    int total = nchunks * 772;
    for (int i = blockIdx.x * 256 + threadIdx.x; i < total; i += gridDim.x * 256) {
        int chunk = i / 772, b = i - chunk * 772;
        int y, x;
        if (b < 194)      { y = 0;   x = b; }
        else if (b < 388) { y = 193; x = b - 194; }
        else { int r = b - 388; y = 1 + (r >> 1); x = (r & 1) ? 193 : 0; }
        size_t g = ((size_t)chunk * PPG + (size_t)y * PH + x) * 8;
        uint4 z = make_uint4(0, 0, 0, 0);
        *(uint4*)&ph[g] = z;
        *(uint4*)&pl[g] = z;
    }
}

// 3x3 SAME conv via split-bf16 MFMA (32x32x16), double-buffered LDS prefetch.
// inh/inl: [NCHUNK][PH][PH][8] bf16 padded planes; wh/wl: [NOB][NCHUNK][10][OTC][8].
// Block: 256 thr (4 waves), 16x16 spatial tile, OTC out channels (NF = OTC/32 n-frags).
// K-step = 16 = 2 tap-slots x 8 ic; 10 tap-slots (slot 9 zero weights) -> 5 k-steps/chunk.
// 32x32x16 operand maps: A row / B col = lane&31; k-octet = lane>>5 (tap select);
// same contiguous-8 k-labeling both sides -> any HW k-permutation cancels.
// C/D (HW-verified): col = lane&31, row m = (reg&3) + 8*(reg>>2) + 4*(lane>>5).
// NOTE: no min-waves hint (rounds 5/8: hint below acc footprint -> scratch spill).
template<int NCHUNK, int OTC, bool LAST>
__global__ __launch_bounds__(256) void conv_mfma(
    const ushort_t* __restrict__ inh, const ushort_t* __restrict__ inl,
    const ushort_t* __restrict__ wth, const ushort_t* __restrict__ wtl,
    const float* __restrict__ bias, int c_out,
    ushort_t* __restrict__ outh, ushort_t* __restrict__ outl, float* __restrict__ outf)
{
    constexpr int NF = OTC / 32;
    constexpr int WSLAB = 10 * OTC * 8;       // ush per weight buffer (one of h/l)
    constexpr int NWIT = WSLAB / 512;         // 64-granule staging iters (10 or 5)
    __shared__ ushort_t s_xh[2 * HGR * 8], s_xl[2 * HGR * 8];   // 2 x 5184 B each
    __shared__ ushort_t s_wh[2 * WSLAB],   s_wl[2 * WSLAB];

    const int tid = threadIdx.x;
    const int wv = tid >> 6;          // 0..3
    const int lane = tid & 63;
    const int ln31 = lane & 31;       // A row (pixel) / B col (o) / D col
    const int lhalf = lane >> 5;      // k-octet -> tap select within k-step
    const int tx0 = (blockIdx.x % 12) * TS;
    const int ty0 = (blockIdx.x / 12) * TS;
    const int ob = blockIdx.y;

    // m-frag = 32 px = 2 rows x 16 cols; wave wv owns frags {2wv, 2wv+1} (rows 4wv..4wv+3)
    const int prow = ln31 >> 4;       // row within 2-row m-frag
    const int pcol = ln31 & 15;
    int pixbase[2];
    #pragma unroll
    for (int mf = 0; mf < 2; ++mf)
        pixbase[mf] = ((wv * 4 + mf * 2 + prow) * HC + pcol) * 8;

    // per-lane tap offset into halo + weight slot, per k-step
    int hof[5], wslot[5];
    #pragma unroll
    for (int ks = 0; ks < 5; ++ks) {
        int t = ks * 2 + lhalf;
        wslot[ks] = t;
        int te = t > 8 ? 8 : t;   // pad slot 9 reads tap8's (valid) address; B there is zero
        int dy = te >= 6 ? 2 : (te >= 3 ? 1 : 0);
        int dx = te - dy * 3;
        hof[ks] = (dy * HC + dx) * 8;
    }

    f32x16 acc[2][NF];
    #pragma unroll
    for (int mf = 0; mf < 2; ++mf)
        #pragma unroll
        for (int nf = 0; nf < NF; ++nf) {
            int o = ob * OTC + nf * 32 + ln31;
            float bv = (o < c_out) ? bias[o] : 0.f;
            #pragma unroll
            for (int r = 0; r < 16; ++r) acc[mf][nf][r] = bv;
        }

    const ushort_t* wbh = wth + (size_t)ob * NCHUNK * WSLAB;
    const ushort_t* wbl = wtl + (size_t)ob * NCHUNK * WSLAB;

    auto stage = [&](int buf, int c8) {
        const ushort_t* ih = inh + (size_t)c8 * PPG * 8;
        const ushort_t* il = inl + (size_t)c8 * PPG * 8;
        ushort_t* dxh = s_xh + buf * (HGR * 8);
        ushort_t* dxl = s_xl + buf * (HGR * 8);
        // halo: 324 granules in 6 x 64-lane iters (last iter 4 lanes)
        for (int j = wv; j < 6; j += 4) {
            int hg = j * 64 + lane;
            if (hg < HGR) {
                int r = hg / HC, c = hg - r * HC;
                size_t sg = ((size_t)(ty0 + r) * PH + (tx0 + c)) * 8;
                gld_lds16(&ih[sg], &dxh[j * 64 * 8]);
                gld_lds16(&il[sg], &dxl[j * 64 * 8]);
            }
        }
        const ushort_t* wch = wbh + (size_t)c8 * WSLAB;
        const ushort_t* wcl = wbl + (size_t)c8 * WSLAB;
        ushort_t* dwh = s_wh + buf * WSLAB;
        ushort_t* dwl = s_wl + buf * WSLAB;
        for (int j = wv; j < NWIT; j += 4) {
            gld_lds16(&wch[(j * 64 + lane) * 8], &dwh[j * 64 * 8]);
            gld_lds16(&wcl[(j * 64 + lane) * 8], &dwl[j * 64 * 8]);
        }
    };

    stage(0, 0);
    __syncthreads();   // drains vmcnt -> buf0 ready

    int cur = 0;
    for (int c8 = 0; c8 < NCHUNK; ++c8) {
        if (c8 + 1 < NCHUNK) stage(cur ^ 1, c8 + 1);   // async prefetch, other buffer

        const ushort_t* xh = s_xh + cur * (HGR * 8);
        const ushort_t* xl = s_xl + cur * (HGR * 8);
        const ushort_t* wh = s_wh + cur * WSLAB;
        const ushort_t* wl = s_wl + cur * WSLAB;
        #pragma unroll
        for (int ks = 0; ks < 5; ++ks) {
            frag8 bh[NF], bl[NF];
            #pragma unroll
            for (int nf = 0; nf < NF; ++nf) {
                int a = (wslot[ks] * OTC + nf * 32 + ln31) * 8;
                bh[nf] = *(const frag8*)&wh[a];
                bl[nf] = *(const frag8*)&wl[a];
            }
            #pragma unroll
            for (int mf = 0; mf < 2; ++mf) {
                int abase = pixbase[mf] + hof[ks];
                frag8 ah = *(const frag8*)&xh[abase];
                frag8 al = *(const frag8*)&xl[abase];
                #pragma unroll
                for (int nf = 0; nf < NF; ++nf) {
                    acc[mf][nf] = __builtin_amdgcn_mfma_f32_32x32x16_bf16(ah, bh[nf], acc[mf][nf], 0, 0, 0);
                    acc[mf][nf] = __builtin_amdgcn_mfma_f32_32x32x16_bf16(ah, bl[nf], acc[mf][nf], 0, 0, 0);
                    acc[mf][nf] = __builtin_amdgcn_mfma_f32_32x32x16_bf16(al, bh[nf], acc[mf][nf], 0, 0, 0);
                }
            }
        }
        __syncthreads();   // joins waves on cur + drains prefetch vmcnt -> next buf ready
        cur ^= 1;
    }

    // ---- epilogue: reg j: m = (j&3) + 8*(j>>2) + 4*lhalf; y += m>>4, x = m&15 ----
    #pragma unroll
    for (int mf = 0; mf < 2; ++mf) {
        #pragma unroll
        for (int nf = 0; nf < NF; ++nf) {
            int o = ob * OTC + nf * 32 + ln31;
            if (o < c_out) {
                #pragma unroll
                for (int i = 0; i < 4; ++i) {   // reg quads j = 4i..4i+3 -> consecutive x
                    int gy = ty0 + wv * 4 + mf * 2 + (i >> 1);
                    int px = tx0 + (i & 1) * 8 + lhalf * 4;
                    if (LAST) {
                        float4 v = make_float4(acc[mf][nf][4 * i + 0], acc[mf][nf][4 * i + 1],
                                               acc[mf][nf][4 * i + 2], acc[mf][nf][4 * i + 3]);
                        *(float4*)&outf[(size_t)o * PLANE + gy * HW + px] = v;
                    } else {
                        size_t g0 = ((size_t)(o >> 3) * PPG + (size_t)(gy + 1) * PH + (px + 1)) * 8 + (o & 7);
                        #pragma unroll
                        for (int r = 0; r < 4; ++r) {
                            ushort_t h, l;
                            split2(acc[mf][nf][4 * i + r], h, l);
                            outh[g0 + (size_t)r * 8] = h;
                            outl[g0 + (size_t)r * 8] = l;
                        }
                    }
                }
            }
        }
    }
}

// One batch image. out[c,y,x] = sum_p ks[p*3+c, y, x] * xpad[c, y+p/5-2, x+p%5-2]
__global__ __launch_bounds__(256) void apply_kernel(
    const float* __restrict__ x, const float* __restrict__ ks,
    float* __restrict__ out)
{
    int tid = blockIdx.x * 256 + threadIdx.x;
    if (tid >= PLANE) return;
    int y = tid / HW;
    int xc = tid - y * HW;

    float acc[3] = {0.f, 0.f, 0.f};
    #pragma unroll
    for (int p = 0; p < 25; ++p) {
        const int di = p / 5, dj = p % 5;
        int yy = y + di - 2, xx = xc + dj - 2;
        bool inb = (yy >= 0 && yy < HW && xx >= 0 && xx < HW);
        #pragma unroll
        for (int c = 0; c < 3; ++c) {
            float kv = ks[((size_t)(p * 3 + c) * HW + y) * HW + xc];
            float xv = inb ? x[((size_t)c * HW + yy) * HW + xx] : 0.f;
            acc[c] = fmaf(kv, xv, acc[c]);
        }
    }
    #pragma unroll
    for (int c = 0; c < 3; ++c)
        out[((size_t)c * HW + y) * HW + xc] = acc[c];
}

extern "C" void kernel_launch(void* const* d_in, const int* in_sizes, int n_in,
                              void* d_out, int out_size, void* d_ws, size_t ws_size,
                              hipStream_t stream) {
    const float* feature_x = (const float*)d_in[0];
    const float* x  = (const float*)d_in[1];
    const float* W1 = (const float*)d_in[2];
    const float* b1 = (const float*)d_in[3];
    const float* W2 = (const float*)d_in[4];
    const float* b2 = (const float*)d_in[5];
    const float* W3 = (const float*)d_in[6];
    const float* b3 = (const float*)d_in[7];
    float* out = (float*)d_out;

    // workspace layout in ushort units, total ~92.4 MB
    const size_t PLN32 = (size_t)32 * PPG * 8;   // 9,634,816 ush
    const size_t PLN8  = (size_t)8 * PPG * 8;    // 2,408,704 ush
    ushort_t* y1h = (ushort_t*)d_ws;
    ushort_t* y1l = y1h + PLN32;
    ushort_t* y2h = y1l + PLN32;
    ushort_t* y2l = y2h + PLN32;
    ushort_t* shared_r = y2l + PLN32;            // max(fxh+fxl, ks) = 5,529,600 ush
    ushort_t* fxh = shared_r;
    ushort_t* fxl = fxh + PLN8;
    float*    ks  = (float*)shared_r;            // [75][PLANE] f32, aliases fx
    ushort_t* w1h = shared_r + 5529600;          // [4][8][10][64][8]  = 163,840
    ushort_t* w1l = w1h + 163840;
    ushort_t* w2h = w1l + 163840;                // [4][32][10][64][8] = 655,360
    ushort_t* w2l = w2h + 655360;
    ushort_t* w3h = w2l + 655360;                // [3][32][10][32][8] = 245,760
    ushort_t* w3l = w3h + 245760;

    dim3 blk256(256);
    // zero padded borders of y1/y2 once (epilogues only write interiors)
    zborder_kernel<<<97, blk256, 0, stream>>>(y1h, y1l, 32);
    zborder_kernel<<<97, blk256, 0, stream>>>(y2h, y2l, 32);
    // weight transforms (shared across batches)
    wtrans_kernel<<<256, blk256, 0, stream>>>(W1, w1h, w1l, 64, 256, 8, 64, 163840);
    wtrans_kernel<<<256, blk256, 0, stream>>>(W2, w2h, w2l, 256, 256, 32, 64, 655360);
    wtrans_kernel<<<256, blk256, 0, stream>>>(W3, w3h, w3l, 256, 75, 32, 32, 245760);

    // 16x16 tiles: 12 x 12 = 144 spatial blocks
    dim3 g12(144, 4), g3(144, 3), ga((PLANE + 255) / 256);
    for (int b = 0; b < 4; ++b) {
        const float* fx_b = feature_x + (size_t)b * 64 * PLANE;
        const float* x_b  = x + (size_t)b * 3 * PLANE;
        float* out_b      = out + (size_t)b * 3 * PLANE;
        packfx_kernel<<<1024, blk256, 0, stream>>>(fx_b, fxh, fxl, 64 * PLANE);
        zborder_kernel<<<25, blk256, 0, stream>>>(fxh, fxl, 8);   // ks aliasing clobbers fx borders
        conv_mfma< 8, 64, false><<<g12, blk256, 0, stream>>>(fxh, fxl, w1h, w1l, b1, 256, y1h, y1l, nullptr);
        conv_mfma<32, 64, false><<<g12, blk256, 0, stream>>>(y1h, y1l, w2h, w2l, b2, 256, y2h, y2l, nullptr);
        conv_mfma<32, 32, true ><<<g3,  blk256, 0, stream>>>(y2h, y2l, w3h, w3l, b3,  75, nullptr, nullptr, ks);
        apply_kernel<<<ga, blk256, 0, stream>>>(x_b, ks, out_b);
    }
}